// Round 1
// baseline (645.230 us; speedup 1.0000x reference)
//
#include <hip/hip_runtime.h>
#include <cstdint>
#include <cstddef>

// Problem constants (from reference)
constexpr int N  = 2048;     // parents
constexpr int C  = 256;      // in channels
constexpr int CO = 128;      // out channels
constexpr int M  = 16384;    // children (8*N)
constexpr int G  = 66;       // padded child grid dim (S2+2)
constexpr float EPS = 1e-6f;

using bf8 = __attribute__((ext_vector_type(8))) short;   // 8 bf16 (4 VGPRs)
using f4  = __attribute__((ext_vector_type(4))) float;   // 4 f32 acc

static __device__ __forceinline__ unsigned short f2bf(float f) {
  unsigned u = __float_as_uint(f);
  u += 0x7fffu + ((u >> 16) & 1u);     // round-to-nearest-even
  return (unsigned short)(u >> 16);
}

// ---------------- init: grid sentinel + zero rows -----------------
__global__ void k_init(int* __restrict__ grid, unsigned short* __restrict__ h,
                       unsigned short* __restrict__ h1) {
  int i = blockIdx.x * 256 + threadIdx.x;
  if (i < G * G * G) grid[i] = M;
  if (i < C)  h[(size_t)N * C + i] = 0;
  if (i < CO) h1[(size_t)M * CO + i] = 0;
}

// ---------------- weight transpose [27][CIN][CO] f32 -> [27][CO][CIN] bf16 ----
template <int CIN>
__global__ void k_wt(const float* __restrict__ w, unsigned short* __restrict__ wt) {
  int i = blockIdx.x * 256 + threadIdx.x;
  if (i >= 27 * CIN * CO) return;
  int c = i % CIN;
  int rest = i / CIN;
  int o = rest % CO;
  int k = rest / CO;
  wt[i] = f2bf(w[((size_t)(k * CIN + c)) * CO + o]);
}

// ---------------- per-parent: subdiv + mask + LN + silu -> h (bf16) ----------
__global__ __launch_bounds__(256) void k_rownorm(
    const float* __restrict__ feats, const float* __restrict__ n1w,
    const float* __restrict__ n1b, const float* __restrict__ sdw,
    const float* __restrict__ sdb, float* __restrict__ out_subdiv,
    unsigned short* __restrict__ h, int* __restrict__ pidx,
    float* __restrict__ maskf) {
  int n = blockIdx.x, t = threadIdx.x;
  float x = feats[(size_t)n * C + t];
  float4 w0 = *(const float4*)(sdw + t * 8);
  float4 w1 = *(const float4*)(sdw + t * 8 + 4);
  float v[10] = {x * w0.x, x * w0.y, x * w0.z, x * w0.w,
                 x * w1.x, x * w1.y, x * w1.z, x * w1.w, x, x * x};
#pragma unroll
  for (int mk = 1; mk < 64; mk <<= 1) {
#pragma unroll
    for (int j = 0; j < 10; ++j) v[j] += __shfl_xor(v[j], mk, 64);
  }
  __shared__ float red[4][10];
  int wave = t >> 6, lane = t & 63;
  if (lane == 0) {
#pragma unroll
    for (int j = 0; j < 10; ++j) red[wave][j] = v[j];
  }
  __syncthreads();
  float sums[10];
#pragma unroll
  for (int j = 0; j < 10; ++j)
    sums[j] = red[0][j] + red[1][j] + red[2][j] + red[3][j];
  float mean = sums[8] / (float)C;
  float var  = sums[9] / (float)C - mean * mean;
  float rstd = rsqrtf(var + EPS);
  if (t < 8) {
    float sd = sums[t] + sdb[t];
    out_subdiv[(size_t)n * 8 + t] = sd;
    bool mk = sd > 0.f;
    pidx[n * 8 + t]  = mk ? n : N;   // h row index (N = zero row)
    maskf[n * 8 + t] = mk ? 1.f : 0.f;
  }
  float y  = (x - mean) * rstd * n1w[t] + n1b[t];
  float sl = y / (1.f + __expf(-y));
  h[(size_t)n * C + t] = f2bf(sl);
}

// ---------------- scatter child ids into grid --------------------------------
__global__ void k_scatter(const int* __restrict__ coords, int* __restrict__ grid) {
  int m = blockIdx.x * 256 + threadIdx.x;
  if (m >= M) return;
  int p = m >> 3, j = m & 7;
  int x = coords[p * 3 + 0] * 2 + ((j >> 2) & 1) + 1;
  int y = coords[p * 3 + 1] * 2 + ((j >> 1) & 1) + 1;
  int z = coords[p * 3 + 2] * 2 + (j & 1) + 1;
  grid[(x * G + y) * G + z] = m;
}

// ---------------- build nidx (child ids) and g1 (h-row ids) ------------------
__global__ void k_nidx(const int* __restrict__ coords, const int* __restrict__ grid,
                       const int* __restrict__ pidx, int* __restrict__ nidx,
                       int* __restrict__ g1) {
  int idx = blockIdx.x * 256 + threadIdx.x;
  if (idx >= M * 27) return;
  int m = idx / 27, k = idx - m * 27;
  int p = m >> 3, j = m & 7;
  int dx = k / 9 - 1;
  int dy = (k / 3) % 3 - 1;
  int dz = k % 3 - 1;
  int x = coords[p * 3 + 0] * 2 + ((j >> 2) & 1) + 1 + dx;
  int y = coords[p * 3 + 1] * 2 + ((j >> 1) & 1) + 1 + dy;
  int z = coords[p * 3 + 2] * 2 + (j & 1) + 1 + dz;
  int gv = grid[(x * G + y) * G + z];
  nidx[idx] = gv;                       // index into h1 (M = zero row)
  g1[idx] = (gv == M) ? N : pidx[gv];   // index into h  (N = zero row)
}

// ---------------- skip GEMM: s = feats @ skip_w + skip_b  (f32) --------------
__global__ __launch_bounds__(256) void k_skip(const float* __restrict__ feats,
                                              const float* __restrict__ skw,
                                              const float* __restrict__ skb,
                                              float* __restrict__ s) {
  __shared__ float tile[32][36];
  int t = threadIdx.x;
  int rb = (blockIdx.x >> 1) * 32;        // 32 rows per block
  int ob = (blockIdx.x & 1) * 64;         // 64-col half
  int o = ob + (t & 63);
  int rg = (t >> 6) * 8;                  // 8 rows per wave-group
  float acc[8] = {0, 0, 0, 0, 0, 0, 0, 0};
  for (int cb = 0; cb < C; cb += 32) {
    __syncthreads();
    int row = t >> 3, cc = (t & 7) * 4;
    *(float4*)&tile[row][cc] =
        *(const float4*)(feats + (size_t)(rb + row) * C + cb + cc);
    __syncthreads();
    for (int c = 0; c < 32; ++c) {
      float wv = skw[(size_t)(cb + c) * CO + o];
#pragma unroll
      for (int r = 0; r < 8; ++r) acc[r] += tile[rg + r][c] * wv;
    }
  }
  float bv = skb[o];
#pragma unroll
  for (int r = 0; r < 8; ++r) s[(size_t)(rb + rg + r) * CO + o] = acc[r] + bv;
}

// ---------------- gather-GEMM conv (MFMA) ------------------------------------
// src: (R+1) x CIN bf16 rows (last row zero); gidx: M x 27 row ids;
// wt: [27][CO][CIN] bf16.  LN_EPI: +bias, LayerNorm(no affine), silu -> bf16 h1.
// else: +bias +skip, *mask -> f32 out.
template <int CIN, bool LN_EPI>
__global__ __launch_bounds__(256) void k_conv(
    const unsigned short* __restrict__ src, const int* __restrict__ gidx,
    const unsigned short* __restrict__ wt, const float* __restrict__ bias,
    const float* __restrict__ sres, const float* __restrict__ maskf,
    unsigned short* __restrict__ h1out, float* __restrict__ out) {
  int t = threadIdx.x;
  int wave = t >> 6, lane = t & 63;
  int quad = lane >> 4, ln = lane & 15;
  int mrow = blockIdx.x * 64 + wave * 16 + ln;   // this lane's A-row (child id)

  f4 acc[8];
  f4 zero = {0.f, 0.f, 0.f, 0.f};
#pragma unroll
  for (int i = 0; i < 8; ++i) acc[i] = zero;

  const int* grow = gidx + (size_t)mrow * 27;
  for (int k = 0; k < 27; ++k) {
    int r = grow[k];
    const unsigned short* arow  = src + (size_t)r * CIN + quad * 8;
    const unsigned short* bbase = wt + ((size_t)(k * CO + ln)) * CIN + quad * 8;
#pragma unroll
    for (int cb = 0; cb < CIN; cb += 32) {
      bf8 af = *(const bf8*)(arow + cb);
#pragma unroll
      for (int tt = 0; tt < 8; ++tt) {
        bf8 bf = *(const bf8*)(bbase + (size_t)tt * 16 * CIN + cb);
        acc[tt] = __builtin_amdgcn_mfma_f32_16x16x32_bf16(af, bf, acc[tt], 0, 0, 0);
      }
    }
  }

  int m0 = blockIdx.x * 64 + wave * 16 + quad * 4;   // rows m0..m0+3 in regs
  float bv[8];
#pragma unroll
  for (int tt = 0; tt < 8; ++tt) bv[tt] = bias[tt * 16 + ln];

  if (LN_EPI) {
#pragma unroll
    for (int r = 0; r < 4; ++r) {
      float sum = 0.f, sq = 0.f;
#pragma unroll
      for (int tt = 0; tt < 8; ++tt) {
        float v = acc[tt][r] + bv[tt];
        acc[tt][r] = v;
        sum += v;
        sq += v * v;
      }
#pragma unroll
      for (int mk = 1; mk < 16; mk <<= 1) {
        sum += __shfl_xor(sum, mk, 64);
        sq  += __shfl_xor(sq, mk, 64);
      }
      float mean = sum / (float)CO;
      float var  = sq / (float)CO - mean * mean;
      float rstd = rsqrtf(var + EPS);
      int row = m0 + r;
#pragma unroll
      for (int tt = 0; tt < 8; ++tt) {
        float y  = (acc[tt][r] - mean) * rstd;
        float sl = y / (1.f + __expf(-y));
        h1out[(size_t)row * CO + tt * 16 + ln] = f2bf(sl);
      }
    }
  } else {
#pragma unroll
    for (int r = 0; r < 4; ++r) {
      int row = m0 + r;
      float mk = maskf[row];
      int parent = row >> 3;
#pragma unroll
      for (int tt = 0; tt < 8; ++tt) {
        float v = acc[tt][r] + bv[tt] + sres[(size_t)parent * CO + tt * 16 + ln];
        out[(size_t)row * CO + tt * 16 + ln] = v * mk;
      }
    }
  }
}

// ---------------- launcher ----------------------------------------------------
extern "C" void kernel_launch(void* const* d_in, const int* in_sizes, int n_in,
                              void* d_out, int out_size, void* d_ws, size_t ws_size,
                              hipStream_t stream) {
  const float* feats = (const float*)d_in[0];
  const float* n1w   = (const float*)d_in[1];
  const float* n1b   = (const float*)d_in[2];
  const float* sdw   = (const float*)d_in[3];
  const float* sdb   = (const float*)d_in[4];
  const float* c1w   = (const float*)d_in[5];
  const float* c1b   = (const float*)d_in[6];
  const float* c2w   = (const float*)d_in[7];
  const float* c2b   = (const float*)d_in[8];
  const float* skw   = (const float*)d_in[9];
  const float* skb   = (const float*)d_in[10];
  const int* coords  = (const int*)d_in[11];
  float* out = (float*)d_out;   // [M*CO] conv output, then [N*8] subdiv

  char* ws = (char*)d_ws;
  size_t off = 0;
  auto alloc = [&](size_t bytes) -> char* {
    char* p = ws + off;
    off += (bytes + 255) & ~(size_t)255;
    return p;
  };
  unsigned short* h    = (unsigned short*)alloc((size_t)(N + 1) * C * 2);
  unsigned short* h1   = (unsigned short*)alloc((size_t)(M + 1) * CO * 2);
  int*   grid  = (int*)alloc((size_t)G * G * G * 4);
  int*   nidx  = (int*)alloc((size_t)M * 27 * 4);
  int*   g1    = (int*)alloc((size_t)M * 27 * 4);
  int*   pidx  = (int*)alloc((size_t)M * 4);
  float* maskf = (float*)alloc((size_t)M * 4);
  float* sres  = (float*)alloc((size_t)N * CO * 4);
  unsigned short* w1t = (unsigned short*)alloc((size_t)27 * CO * C * 2);
  unsigned short* w2t = (unsigned short*)alloc((size_t)27 * CO * CO * 2);

  k_init<<<(G * G * G + 255) / 256, 256, 0, stream>>>(grid, h, h1);
  k_wt<C><<<(27 * C * CO + 255) / 256, 256, 0, stream>>>(c1w, w1t);
  k_wt<CO><<<(27 * CO * CO + 255) / 256, 256, 0, stream>>>(c2w, w2t);
  k_rownorm<<<N, 256, 0, stream>>>(feats, n1w, n1b, sdw, sdb,
                                   out + (size_t)M * CO, h, pidx, maskf);
  k_scatter<<<(M + 255) / 256, 256, 0, stream>>>(coords, grid);
  k_nidx<<<(M * 27 + 255) / 256, 256, 0, stream>>>(coords, grid, pidx, nidx, g1);
  k_skip<<<128, 256, 0, stream>>>(feats, skw, skb, sres);
  k_conv<C, true><<<M / 64, 256, 0, stream>>>(h, g1, w1t, c1b, nullptr, nullptr,
                                              h1, nullptr);
  k_conv<CO, false><<<M / 64, 256, 0, stream>>>(h1, nidx, w2t, c2b, sres, maskf,
                                                nullptr, out);
}

// Round 2
// 459.906 us; speedup vs baseline: 1.4030x; 1.4030x over previous
//
#include <hip/hip_runtime.h>
#include <cstdint>
#include <cstddef>

// Problem constants (from reference)
constexpr int N  = 2048;     // parents
constexpr int C  = 256;      // in channels
constexpr int CO = 128;      // out channels
constexpr int M  = 16384;    // children (8*N)
constexpr int G  = 66;       // padded child grid dim (S2+2)
constexpr float EPS = 1e-6f;

using bf8 = __attribute__((ext_vector_type(8))) short;   // 8 bf16 (4 VGPRs)
using f4  = __attribute__((ext_vector_type(4))) float;   // 4 f32 acc

static __device__ __forceinline__ unsigned short f2bf(float f) {
  unsigned u = __float_as_uint(f);
  u += 0x7fffu + ((u >> 16) & 1u);     // round-to-nearest-even
  return (unsigned short)(u >> 16);
}

// ---------------- init: grid sentinel + zero rows -----------------
__global__ void k_init(int* __restrict__ grid, unsigned short* __restrict__ h,
                       unsigned short* __restrict__ h1) {
  int i = blockIdx.x * 256 + threadIdx.x;
  if (i < G * G * G) grid[i] = M;
  if (i < C)  h[(size_t)N * C + i] = 0;
  if (i < CO) h1[(size_t)M * CO + i] = 0;
}

// ---------------- weight transpose [27][CIN][CO] f32 -> [27][CO][CIN] bf16 ----
template <int CIN>
__global__ void k_wt(const float* __restrict__ w, unsigned short* __restrict__ wt) {
  int i = blockIdx.x * 256 + threadIdx.x;
  if (i >= 27 * CIN * CO) return;
  int c = i % CIN;
  int rest = i / CIN;
  int o = rest % CO;
  int k = rest / CO;
  wt[i] = f2bf(w[((size_t)(k * CIN + c)) * CO + o]);
}

// ---------------- per-parent: subdiv + mask + LN + silu -> h (bf16) ----------
__global__ __launch_bounds__(256) void k_rownorm(
    const float* __restrict__ feats, const float* __restrict__ n1w,
    const float* __restrict__ n1b, const float* __restrict__ sdw,
    const float* __restrict__ sdb, float* __restrict__ out_subdiv,
    unsigned short* __restrict__ h, int* __restrict__ pidx,
    float* __restrict__ maskf) {
  int n = blockIdx.x, t = threadIdx.x;
  float x = feats[(size_t)n * C + t];
  float4 w0 = *(const float4*)(sdw + t * 8);
  float4 w1 = *(const float4*)(sdw + t * 8 + 4);
  float v[10] = {x * w0.x, x * w0.y, x * w0.z, x * w0.w,
                 x * w1.x, x * w1.y, x * w1.z, x * w1.w, x, x * x};
#pragma unroll
  for (int mk = 1; mk < 64; mk <<= 1) {
#pragma unroll
    for (int j = 0; j < 10; ++j) v[j] += __shfl_xor(v[j], mk, 64);
  }
  __shared__ float red[4][10];
  int wave = t >> 6, lane = t & 63;
  if (lane == 0) {
#pragma unroll
    for (int j = 0; j < 10; ++j) red[wave][j] = v[j];
  }
  __syncthreads();
  float sums[10];
#pragma unroll
  for (int j = 0; j < 10; ++j)
    sums[j] = red[0][j] + red[1][j] + red[2][j] + red[3][j];
  float mean = sums[8] / (float)C;
  float var  = sums[9] / (float)C - mean * mean;
  float rstd = rsqrtf(var + EPS);
  if (t < 8) {
    float sd = sums[t] + sdb[t];
    out_subdiv[(size_t)n * 8 + t] = sd;
    bool mk = sd > 0.f;
    pidx[n * 8 + t]  = mk ? n : N;   // h row index (N = zero row)
    maskf[n * 8 + t] = mk ? 1.f : 0.f;
  }
  float y  = (x - mean) * rstd * n1w[t] + n1b[t];
  float sl = y / (1.f + __expf(-y));
  h[(size_t)n * C + t] = f2bf(sl);
}

// ---------------- scatter child ids into grid --------------------------------
__global__ void k_scatter(const int* __restrict__ coords, int* __restrict__ grid) {
  int m = blockIdx.x * 256 + threadIdx.x;
  if (m >= M) return;
  int p = m >> 3, j = m & 7;
  int x = coords[p * 3 + 0] * 2 + ((j >> 2) & 1) + 1;
  int y = coords[p * 3 + 1] * 2 + ((j >> 1) & 1) + 1;
  int z = coords[p * 3 + 2] * 2 + (j & 1) + 1;
  grid[(x * G + y) * G + z] = m;
}

// ---------------- build nidx (child ids) and g1 (h-row ids) ------------------
__global__ void k_nidx(const int* __restrict__ coords, const int* __restrict__ grid,
                       const int* __restrict__ pidx, int* __restrict__ nidx,
                       int* __restrict__ g1) {
  int idx = blockIdx.x * 256 + threadIdx.x;
  if (idx >= M * 27) return;
  int m = idx / 27, k = idx - m * 27;
  int p = m >> 3, j = m & 7;
  int dx = k / 9 - 1;
  int dy = (k / 3) % 3 - 1;
  int dz = k % 3 - 1;
  int x = coords[p * 3 + 0] * 2 + ((j >> 2) & 1) + 1 + dx;
  int y = coords[p * 3 + 1] * 2 + ((j >> 1) & 1) + 1 + dy;
  int z = coords[p * 3 + 2] * 2 + (j & 1) + 1 + dz;
  int gv = grid[(x * G + y) * G + z];
  nidx[idx] = gv;                       // index into h1 (M = zero row)
  g1[idx] = (gv == M) ? N : pidx[gv];   // index into h  (N = zero row)
}

// ---------------- skip GEMM: s = feats @ skip_w + skip_b  (f32) --------------
__global__ __launch_bounds__(256) void k_skip(const float* __restrict__ feats,
                                              const float* __restrict__ skw,
                                              const float* __restrict__ skb,
                                              float* __restrict__ s) {
  __shared__ float tile[32][36];
  int t = threadIdx.x;
  int rb = (blockIdx.x >> 1) * 32;        // 32 rows per block
  int ob = (blockIdx.x & 1) * 64;         // 64-col half
  int o = ob + (t & 63);
  int rg = (t >> 6) * 8;                  // 8 rows per wave-group
  float acc[8] = {0, 0, 0, 0, 0, 0, 0, 0};
  for (int cb = 0; cb < C; cb += 32) {
    __syncthreads();
    int row = t >> 3, cc = (t & 7) * 4;
    *(float4*)&tile[row][cc] =
        *(const float4*)(feats + (size_t)(rb + row) * C + cb + cc);
    __syncthreads();
    for (int c = 0; c < 32; ++c) {
      float wv = skw[(size_t)(cb + c) * CO + o];
#pragma unroll
      for (int r = 0; r < 8; ++r) acc[r] += tile[rg + r][c] * wv;
    }
  }
  float bv = skb[o];
#pragma unroll
  for (int r = 0; r < 8; ++r) s[(size_t)(rb + rg + r) * CO + o] = acc[r] + bv;
}

// ---------------- gather-GEMM conv (MFMA), k-split + co-split ----------------
// Each block: 64 child rows x 64 output cols x k-neighbor subrange.
// grid = (M/64 * 2, 2): x -> (rowblk, cohalf), y -> kpart.
// Writes f32 partials: part[kpart][m][co]. Bias/epilogue applied in reduce.
// 1-deep software pipeline: prefetch next (k,cb) A/B frags + next gather idx.
template <int CIN, int LNB, int KSPLIT>
__global__ __launch_bounds__(256, 4) void k_conv(
    const unsigned short* __restrict__ src, const int* __restrict__ gidx,
    const unsigned short* __restrict__ wt, float* __restrict__ part) {
  constexpr int NB = 1 << LNB;            // CIN/32 chunks
  int t = threadIdx.x;
  int wave = t >> 6, lane = t & 63;
  int quad = lane >> 4, ln = lane & 15;
  int rowblk = blockIdx.x >> 1;
  int cohalf = blockIdx.x & 1;
  int kpart = blockIdx.y;
  int k0 = kpart * KSPLIT;
  int nk = min(27 - k0, KSPLIT);
  int mrow = rowblk * 64 + wave * 16 + ln;     // this lane's A-row (child id)

  const int* grow = gidx + (size_t)mrow * 27 + k0;
  const unsigned short* wbase =
      wt + ((size_t)(k0 * CO + cohalf * 64 + ln)) * CIN + quad * 8;
  const unsigned short* abase = src + (size_t)quad * 8;

  f4 acc[4];
  f4 zero = {0.f, 0.f, 0.f, 0.f};
#pragma unroll
  for (int i = 0; i < 4; ++i) acc[i] = zero;

  // prologue: load frags for (k=0, cb=0)
  int r = grow[0];
  bf8 a = *(const bf8*)(abase + (size_t)r * CIN);
  bf8 b0 = *(const bf8*)(wbase + 0 * 16 * CIN);
  bf8 b1 = *(const bf8*)(wbase + 1 * 16 * CIN);
  bf8 b2 = *(const bf8*)(wbase + 2 * 16 * CIN);
  bf8 b3 = *(const bf8*)(wbase + 3 * 16 * CIN);

  for (int k = 0; k < nk; ++k) {
    int rn = (k + 1 < nk) ? grow[k + 1] : 0;   // wave-uniform condition
    const unsigned short* wk = wbase + (size_t)k * CO * CIN;
#pragma unroll
    for (int cb = 0; cb < NB; ++cb) {
      bf8 an, bn0, bn1, bn2, bn3;
      bool have = true;
      if (cb + 1 < NB) {
        const unsigned short* w2 = wk + (cb + 1) * 32;
        an  = *(const bf8*)(abase + (size_t)r * CIN + (cb + 1) * 32);
        bn0 = *(const bf8*)(w2 + 0 * 16 * CIN);
        bn1 = *(const bf8*)(w2 + 1 * 16 * CIN);
        bn2 = *(const bf8*)(w2 + 2 * 16 * CIN);
        bn3 = *(const bf8*)(w2 + 3 * 16 * CIN);
      } else if (k + 1 < nk) {
        const unsigned short* w2 = wk + (size_t)CO * CIN;
        an  = *(const bf8*)(abase + (size_t)rn * CIN);
        bn0 = *(const bf8*)(w2 + 0 * 16 * CIN);
        bn1 = *(const bf8*)(w2 + 1 * 16 * CIN);
        bn2 = *(const bf8*)(w2 + 2 * 16 * CIN);
        bn3 = *(const bf8*)(w2 + 3 * 16 * CIN);
      } else {
        have = false;
      }
      acc[0] = __builtin_amdgcn_mfma_f32_16x16x32_bf16(a, b0, acc[0], 0, 0, 0);
      acc[1] = __builtin_amdgcn_mfma_f32_16x16x32_bf16(a, b1, acc[1], 0, 0, 0);
      acc[2] = __builtin_amdgcn_mfma_f32_16x16x32_bf16(a, b2, acc[2], 0, 0, 0);
      acc[3] = __builtin_amdgcn_mfma_f32_16x16x32_bf16(a, b3, acc[3], 0, 0, 0);
      if (have) { a = an; b0 = bn0; b1 = bn1; b2 = bn2; b3 = bn3; }
    }
    r = rn;
  }

  // store partials (D layout: col = ln, row = quad*4 + rr)
  int m0 = rowblk * 64 + wave * 16 + quad * 4;
  float* pp = part + (size_t)kpart * M * CO;
#pragma unroll
  for (int tt = 0; tt < 4; ++tt) {
#pragma unroll
    for (int rr = 0; rr < 4; ++rr) {
      pp[(size_t)(m0 + rr) * CO + cohalf * 64 + tt * 16 + ln] = acc[tt][rr];
    }
  }
}

// ---------------- reduce 1: sum partials + bias + LN(no affine) + silu -> h1 -
__global__ __launch_bounds__(256) void k_r1(const float* __restrict__ p,
                                            const float* __restrict__ bias,
                                            unsigned short* __restrict__ h1) {
  int wave = threadIdx.x >> 6, lane = threadIdx.x & 63;
  int m = blockIdx.x * 4 + wave;
  const float* p0 = p + (size_t)m * CO;
  const float* p1 = p + (size_t)(M + m) * CO;
  float v0 = p0[lane] + p1[lane] + bias[lane];
  float v1 = p0[lane + 64] + p1[lane + 64] + bias[lane + 64];
  float sum = v0 + v1, sq = v0 * v0 + v1 * v1;
#pragma unroll
  for (int mk = 1; mk < 64; mk <<= 1) {
    sum += __shfl_xor(sum, mk, 64);
    sq  += __shfl_xor(sq, mk, 64);
  }
  float mean = sum / (float)CO;
  float var  = sq / (float)CO - mean * mean;
  float rstd = rsqrtf(var + EPS);
  float y0 = (v0 - mean) * rstd;
  float y1 = (v1 - mean) * rstd;
  float s0 = y0 / (1.f + __expf(-y0));
  float s1 = y1 / (1.f + __expf(-y1));
  h1[(size_t)m * CO + lane]      = f2bf(s0);
  h1[(size_t)m * CO + lane + 64] = f2bf(s1);
}

// ---------------- reduce 2: sum partials + bias + skip, *mask -> out f32 -----
__global__ __launch_bounds__(256) void k_r2(const float* __restrict__ p,
                                            const float* __restrict__ bias,
                                            const float* __restrict__ sres,
                                            const float* __restrict__ maskf,
                                            float* __restrict__ out) {
  int i = blockIdx.x * 256 + threadIdx.x;   // i in [0, M*CO/4)
  int m = i >> 5;                            // 32 float4 per row
  int o4 = (i & 31) * 4;
  float4 a  = *(const float4*)(p + (size_t)m * CO + o4);
  float4 b  = *(const float4*)(p + (size_t)(M + m) * CO + o4);
  float4 bb = *(const float4*)(bias + o4);
  float4 s  = *(const float4*)(sres + (size_t)(m >> 3) * CO + o4);
  float mk = maskf[m];
  float4 r;
  r.x = (a.x + b.x + bb.x + s.x) * mk;
  r.y = (a.y + b.y + bb.y + s.y) * mk;
  r.z = (a.z + b.z + bb.z + s.z) * mk;
  r.w = (a.w + b.w + bb.w + s.w) * mk;
  *(float4*)(out + (size_t)m * CO + o4) = r;
}

// ---------------- launcher ----------------------------------------------------
extern "C" void kernel_launch(void* const* d_in, const int* in_sizes, int n_in,
                              void* d_out, int out_size, void* d_ws, size_t ws_size,
                              hipStream_t stream) {
  const float* feats = (const float*)d_in[0];
  const float* n1w   = (const float*)d_in[1];
  const float* n1b   = (const float*)d_in[2];
  const float* sdw   = (const float*)d_in[3];
  const float* sdb   = (const float*)d_in[4];
  const float* c1w   = (const float*)d_in[5];
  const float* c1b   = (const float*)d_in[6];
  const float* c2w   = (const float*)d_in[7];
  const float* c2b   = (const float*)d_in[8];
  const float* skw   = (const float*)d_in[9];
  const float* skb   = (const float*)d_in[10];
  const int* coords  = (const int*)d_in[11];
  float* out = (float*)d_out;   // [M*CO] conv output, then [N*8] subdiv

  char* ws = (char*)d_ws;
  size_t off = 0;
  auto alloc = [&](size_t bytes) -> char* {
    char* p = ws + off;
    off += (bytes + 255) & ~(size_t)255;
    return p;
  };
  unsigned short* h    = (unsigned short*)alloc((size_t)(N + 1) * C * 2);
  unsigned short* h1   = (unsigned short*)alloc((size_t)(M + 1) * CO * 2);
  int*   grid  = (int*)alloc((size_t)G * G * G * 4);
  int*   nidx  = (int*)alloc((size_t)M * 27 * 4);
  int*   g1    = (int*)alloc((size_t)M * 27 * 4);
  int*   pidx  = (int*)alloc((size_t)M * 4);
  float* maskf = (float*)alloc((size_t)M * 4);
  float* sres  = (float*)alloc((size_t)N * CO * 4);
  unsigned short* w1t = (unsigned short*)alloc((size_t)27 * CO * C * 2);
  unsigned short* w2t = (unsigned short*)alloc((size_t)27 * CO * CO * 2);
  float* pc = (float*)alloc((size_t)2 * M * CO * 4);   // k-split partials (reused)

  k_init<<<(G * G * G + 255) / 256, 256, 0, stream>>>(grid, h, h1);
  k_wt<C><<<(27 * C * CO + 255) / 256, 256, 0, stream>>>(c1w, w1t);
  k_wt<CO><<<(27 * CO * CO + 255) / 256, 256, 0, stream>>>(c2w, w2t);
  k_rownorm<<<N, 256, 0, stream>>>(feats, n1w, n1b, sdw, sdb,
                                   out + (size_t)M * CO, h, pidx, maskf);
  k_scatter<<<(M + 255) / 256, 256, 0, stream>>>(coords, grid);
  k_nidx<<<(M * 27 + 255) / 256, 256, 0, stream>>>(coords, grid, pidx, nidx, g1);
  k_skip<<<128, 256, 0, stream>>>(feats, skw, skb, sres);

  // conv1: C=256 in, k-split 14+13, co-split 2 -> 1024 blocks
  k_conv<C, 3, 14><<<dim3(M / 64 * 2, 2), 256, 0, stream>>>(h, g1, w1t, pc);
  k_r1<<<M / 4, 256, 0, stream>>>(pc, c1b, h1);

  // conv2: 128 in (reuses pc)
  k_conv<CO, 2, 14><<<dim3(M / 64 * 2, 2), 256, 0, stream>>>(h1, nidx, w2t, pc);
  k_r2<<<M * 32 / 256, 256, 0, stream>>>(pc, c2b, sres, maskf, out);
}

// Round 3
// 209.821 us; speedup vs baseline: 3.0751x; 2.1919x over previous
//
#include <hip/hip_runtime.h>
#include <cstdint>
#include <cstddef>

// Problem constants (from reference)
constexpr int N  = 2048;     // parents
constexpr int C  = 256;      // in channels
constexpr int CO = 128;      // out channels
constexpr int M  = 16384;    // children (8*N)
constexpr int G  = 66;       // padded child grid dim (S2+2)
constexpr int KP = 4;        // k-split parts
constexpr int KCHUNK = 7;    // neighbors per part (7,7,7,6)
constexpr float EPS = 1e-6f;

using bf8 = __attribute__((ext_vector_type(8))) short;   // 8 bf16 (4 VGPRs)
using f4  = __attribute__((ext_vector_type(4))) float;   // 4 f32 acc

#define AS1 __attribute__((address_space(1)))
#define AS3 __attribute__((address_space(3)))

// async global->LDS DMA, 16B per lane; LDS dest = wave-uniform base + lane*16
static __device__ __forceinline__ void gl_lds16(const void* g, void* l) {
  __builtin_amdgcn_global_load_lds((AS1 const void*)g, (AS3 void*)l, 16, 0, 0);
}

static __device__ __forceinline__ unsigned short f2bf(float f) {
  unsigned u = __float_as_uint(f);
  u += 0x7fffu + ((u >> 16) & 1u);     // round-to-nearest-even
  return (unsigned short)(u >> 16);
}

// ---------------- init: grid sentinel + zero rows -----------------
__global__ void k_init(int* __restrict__ grid, unsigned short* __restrict__ h,
                       unsigned short* __restrict__ h1) {
  int i = blockIdx.x * 256 + threadIdx.x;
  if (i < G * G * G) grid[i] = M;
  if (i < C)  h[(size_t)N * C + i] = 0;
  if (i < CO) h1[(size_t)M * CO + i] = 0;
}

// ---------------- weight transpose [27][CIN][CO] f32 -> [27][CO][CIN] bf16 ----
template <int CIN>
__global__ void k_wt(const float* __restrict__ w, unsigned short* __restrict__ wt) {
  int i = blockIdx.x * 256 + threadIdx.x;
  if (i >= 27 * CIN * CO) return;
  int c = i % CIN;
  int rest = i / CIN;
  int o = rest % CO;
  int k = rest / CO;
  wt[i] = f2bf(w[((size_t)(k * CIN + c)) * CO + o]);
}

// ---------------- per-parent: subdiv + mask + LN + silu -> h (bf16) ----------
__global__ __launch_bounds__(256) void k_rownorm(
    const float* __restrict__ feats, const float* __restrict__ n1w,
    const float* __restrict__ n1b, const float* __restrict__ sdw,
    const float* __restrict__ sdb, float* __restrict__ out_subdiv,
    unsigned short* __restrict__ h, int* __restrict__ pidx,
    float* __restrict__ maskf) {
  int n = blockIdx.x, t = threadIdx.x;
  float x = feats[(size_t)n * C + t];
  float4 w0 = *(const float4*)(sdw + t * 8);
  float4 w1 = *(const float4*)(sdw + t * 8 + 4);
  float v[10] = {x * w0.x, x * w0.y, x * w0.z, x * w0.w,
                 x * w1.x, x * w1.y, x * w1.z, x * w1.w, x, x * x};
#pragma unroll
  for (int mk = 1; mk < 64; mk <<= 1) {
#pragma unroll
    for (int j = 0; j < 10; ++j) v[j] += __shfl_xor(v[j], mk, 64);
  }
  __shared__ float red[4][10];
  int wave = t >> 6, lane = t & 63;
  if (lane == 0) {
#pragma unroll
    for (int j = 0; j < 10; ++j) red[wave][j] = v[j];
  }
  __syncthreads();
  float sums[10];
#pragma unroll
  for (int j = 0; j < 10; ++j)
    sums[j] = red[0][j] + red[1][j] + red[2][j] + red[3][j];
  float mean = sums[8] / (float)C;
  float var  = sums[9] / (float)C - mean * mean;
  float rstd = rsqrtf(var + EPS);
  if (t < 8) {
    float sd = sums[t] + sdb[t];
    out_subdiv[(size_t)n * 8 + t] = sd;
    bool mk = sd > 0.f;
    pidx[n * 8 + t]  = mk ? n : N;   // h row index (N = zero row)
    maskf[n * 8 + t] = mk ? 1.f : 0.f;
  }
  float y  = (x - mean) * rstd * n1w[t] + n1b[t];
  float sl = y / (1.f + __expf(-y));
  h[(size_t)n * C + t] = f2bf(sl);
}

// ---------------- scatter child ids into grid --------------------------------
__global__ void k_scatter(const int* __restrict__ coords, int* __restrict__ grid) {
  int m = blockIdx.x * 256 + threadIdx.x;
  if (m >= M) return;
  int p = m >> 3, j = m & 7;
  int x = coords[p * 3 + 0] * 2 + ((j >> 2) & 1) + 1;
  int y = coords[p * 3 + 1] * 2 + ((j >> 1) & 1) + 1;
  int z = coords[p * 3 + 2] * 2 + (j & 1) + 1;
  grid[(x * G + y) * G + z] = m;
}

// ---------------- build transposed tables nidxt[k][M], g1t[k][M] -------------
__global__ void k_nidx(const int* __restrict__ coords, const int* __restrict__ grid,
                       const int* __restrict__ pidx, int* __restrict__ nidxt,
                       int* __restrict__ g1t) {
  int idx = blockIdx.x * 256 + threadIdx.x;
  if (idx >= M * 27) return;
  int m = idx & (M - 1);          // M = 2^14
  int k = idx >> 14;
  int p = m >> 3, j = m & 7;
  int dx = k / 9 - 1;
  int dy = (k / 3) % 3 - 1;
  int dz = k % 3 - 1;
  int x = coords[p * 3 + 0] * 2 + ((j >> 2) & 1) + 1 + dx;
  int y = coords[p * 3 + 1] * 2 + ((j >> 1) & 1) + 1 + dy;
  int z = coords[p * 3 + 2] * 2 + (j & 1) + 1 + dz;
  int gv = grid[(x * G + y) * G + z];
  nidxt[idx] = gv;                      // index into h1 (M = zero row)
  g1t[idx] = (gv == M) ? N : pidx[gv];  // index into h  (N = zero row)
}

// ---------------- skip GEMM: s = feats @ skip_w + skip_b  (f32) --------------
__global__ __launch_bounds__(256) void k_skip(const float* __restrict__ feats,
                                              const float* __restrict__ skw,
                                              const float* __restrict__ skb,
                                              float* __restrict__ s) {
  __shared__ float tile[32][36];
  int t = threadIdx.x;
  int rb = (blockIdx.x >> 1) * 32;        // 32 rows per block
  int ob = (blockIdx.x & 1) * 64;         // 64-col half
  int o = ob + (t & 63);
  int rg = (t >> 6) * 8;                  // 8 rows per wave-group
  float acc[8] = {0, 0, 0, 0, 0, 0, 0, 0};
  for (int cb = 0; cb < C; cb += 32) {
    __syncthreads();
    int row = t >> 3, cc = (t & 7) * 4;
    *(float4*)&tile[row][cc] =
        *(const float4*)(feats + (size_t)(rb + row) * C + cb + cc);
    __syncthreads();
    for (int c = 0; c < 32; ++c) {
      float wv = skw[(size_t)(cb + c) * CO + o];
#pragma unroll
      for (int r = 0; r < 8; ++r) acc[r] += tile[rg + r][c] * wv;
    }
  }
  float bv = skb[o];
#pragma unroll
  for (int r = 0; r < 8; ++r) s[(size_t)(rb + rg + r) * CO + o] = acc[r] + bv;
}

// ---------------- implicit-GEMM conv (MFMA + LDS double-buffer) --------------
// Block: 128 child rows x 128 out cols, k-neighbor subrange (KP-way split).
// grid = (M/128, KP). Per stage: one (k, 64-chan chunk); A gathered via
// global_load_lds (per-lane addr), B coalesced; XOR chunk-swizzle in LDS.
// 4 waves (2x2), each 64x64 via 16 16x16x32 tiles. Partials f32 -> reduce.
template <int CIN, int NCB>
__global__ __launch_bounds__(256) void k_conv(
    const unsigned short* __restrict__ src, const int* __restrict__ gt,
    const unsigned short* __restrict__ wt, float* __restrict__ part) {
  __shared__ unsigned short sA[2][128 * 64];   // 16 KB per buf
  __shared__ unsigned short sB[2][128 * 64];
  const int t = threadIdx.x;
  const int w = t >> 6, lane = t & 63;
  const int quad = lane >> 4, ln = lane & 15;
  const int m0 = blockIdx.x * 128;
  const int kpart = blockIdx.y;
  const int k0 = kpart * KCHUNK;
  const int nk = min(KCHUNK, 27 - k0);
  const int nstage = nk * NCB;
  const int rh = (w >> 1) * 64, ch = (w & 1) * 64;

  // staging lane constants: lane covers row seg*8+sr, stored chunk lane&7,
  // which holds global chunk gc = (lane&7) ^ (row&7) = (lane&7) ^ sr
  const int sr = lane >> 3;
  const int gc = (lane & 7) ^ sr;

  auto stage = [&](int s, int buf) {
    const int kk = k0 + s / NCB;
    const int cb = s - (s / NCB) * NCB;
    const int colbase = cb * 64 + gc * 8;      // element offset in source row
    const int* gk = gt + (size_t)kk * M + m0;
#pragma unroll
    for (int tt = 0; tt < 4; ++tt) {
      const int seg = w * 4 + tt;
      const int r = seg * 8 + sr;
      const int ga = gk[r];
      gl_lds16(src + (size_t)ga * CIN + colbase, &sA[buf][seg * 512]);
      gl_lds16(wt + ((size_t)kk * CO + r) * CIN + colbase, &sB[buf][seg * 512]);
    }
  };

  f4 acc[16];
  f4 zero = {0.f, 0.f, 0.f, 0.f};
#pragma unroll
  for (int i = 0; i < 16; ++i) acc[i] = zero;

  stage(0, 0);
  for (int s = 0; s < nstage; ++s) {
    __syncthreads();                 // staging of buf[s&1] done; prev readers done
    if (s + 1 < nstage) stage(s + 1, (s + 1) & 1);
    const unsigned short* pa = sA[s & 1];
    const unsigned short* pb = sB[s & 1];
#pragma unroll
    for (int kc = 0; kc < 2; ++kc) {
      bf8 av[4], bv[4];
#pragma unroll
      for (int ti = 0; ti < 4; ++ti) {
        int row = rh + ti * 16 + ln;
        int sc = (kc * 4 + quad) ^ (row & 7);
        av[ti] = *(const bf8*)(pa + row * 64 + sc * 8);
      }
#pragma unroll
      for (int tj = 0; tj < 4; ++tj) {
        int row = ch + tj * 16 + ln;
        int sc = (kc * 4 + quad) ^ (row & 7);
        bv[tj] = *(const bf8*)(pb + row * 64 + sc * 8);
      }
#pragma unroll
      for (int ti = 0; ti < 4; ++ti)
#pragma unroll
        for (int tj = 0; tj < 4; ++tj)
          acc[ti * 4 + tj] = __builtin_amdgcn_mfma_f32_16x16x32_bf16(
              av[ti], bv[tj], acc[ti * 4 + tj], 0, 0, 0);
    }
  }

  // store partials: D layout col=ln, row=quad*4+rr
  float* pp = part + ((size_t)kpart * M + m0) * CO;
#pragma unroll
  for (int ti = 0; ti < 4; ++ti) {
    int mrow = rh + ti * 16 + quad * 4;
#pragma unroll
    for (int tj = 0; tj < 4; ++tj) {
      int co = ch + tj * 16 + ln;
#pragma unroll
      for (int rr = 0; rr < 4; ++rr)
        pp[(size_t)(mrow + rr) * CO + co] = acc[ti * 4 + tj][rr];
    }
  }
}

// ---------------- reduce 1: sum KP partials + bias + LN + silu -> h1 bf16 ----
__global__ __launch_bounds__(256) void k_r1(const float* __restrict__ p,
                                            const float* __restrict__ bias,
                                            unsigned short* __restrict__ h1) {
  int wave = threadIdx.x >> 6, lane = threadIdx.x & 63;
  int m = blockIdx.x * 4 + wave;
  float v0 = bias[lane], v1 = bias[lane + 64];
#pragma unroll
  for (int q = 0; q < KP; ++q) {
    const float* pq = p + ((size_t)q * M + m) * CO;
    v0 += pq[lane];
    v1 += pq[lane + 64];
  }
  float sum = v0 + v1, sq = v0 * v0 + v1 * v1;
#pragma unroll
  for (int mk = 1; mk < 64; mk <<= 1) {
    sum += __shfl_xor(sum, mk, 64);
    sq  += __shfl_xor(sq, mk, 64);
  }
  float mean = sum / (float)CO;
  float var  = sq / (float)CO - mean * mean;
  float rstd = rsqrtf(var + EPS);
  float y0 = (v0 - mean) * rstd;
  float y1 = (v1 - mean) * rstd;
  float s0 = y0 / (1.f + __expf(-y0));
  float s1 = y1 / (1.f + __expf(-y1));
  h1[(size_t)m * CO + lane]      = f2bf(s0);
  h1[(size_t)m * CO + lane + 64] = f2bf(s1);
}

// ---------------- reduce 2: sum KP partials + bias + skip, *mask -> out ------
__global__ __launch_bounds__(256) void k_r2(const float* __restrict__ p,
                                            const float* __restrict__ bias,
                                            const float* __restrict__ sres,
                                            const float* __restrict__ maskf,
                                            float* __restrict__ out) {
  int i = blockIdx.x * 256 + threadIdx.x;   // i in [0, M*CO/4)
  int m = i >> 5;                            // 32 float4 per row
  int o4 = (i & 31) * 4;
  float4 acc = *(const float4*)(bias + o4);
#pragma unroll
  for (int q = 0; q < KP; ++q) {
    float4 a = *(const float4*)(p + ((size_t)q * M + m) * CO + o4);
    acc.x += a.x; acc.y += a.y; acc.z += a.z; acc.w += a.w;
  }
  float4 s = *(const float4*)(sres + (size_t)(m >> 3) * CO + o4);
  float mk = maskf[m];
  float4 r;
  r.x = (acc.x + s.x) * mk;
  r.y = (acc.y + s.y) * mk;
  r.z = (acc.z + s.z) * mk;
  r.w = (acc.w + s.w) * mk;
  *(float4*)(out + (size_t)m * CO + o4) = r;
}

// ---------------- launcher ----------------------------------------------------
extern "C" void kernel_launch(void* const* d_in, const int* in_sizes, int n_in,
                              void* d_out, int out_size, void* d_ws, size_t ws_size,
                              hipStream_t stream) {
  const float* feats = (const float*)d_in[0];
  const float* n1w   = (const float*)d_in[1];
  const float* n1b   = (const float*)d_in[2];
  const float* sdw   = (const float*)d_in[3];
  const float* sdb   = (const float*)d_in[4];
  const float* c1w   = (const float*)d_in[5];
  const float* c1b   = (const float*)d_in[6];
  const float* c2w   = (const float*)d_in[7];
  const float* c2b   = (const float*)d_in[8];
  const float* skw   = (const float*)d_in[9];
  const float* skb   = (const float*)d_in[10];
  const int* coords  = (const int*)d_in[11];
  float* out = (float*)d_out;   // [M*CO] conv output, then [N*8] subdiv

  char* ws = (char*)d_ws;
  size_t off = 0;
  auto alloc = [&](size_t bytes) -> char* {
    char* p = ws + off;
    off += (bytes + 255) & ~(size_t)255;
    return p;
  };
  unsigned short* h    = (unsigned short*)alloc((size_t)(N + 1) * C * 2);
  unsigned short* h1   = (unsigned short*)alloc((size_t)(M + 1) * CO * 2);
  int*   grid  = (int*)alloc((size_t)G * G * G * 4);
  int*   nidxt = (int*)alloc((size_t)27 * M * 4);
  int*   g1t   = (int*)alloc((size_t)27 * M * 4);
  int*   pidx  = (int*)alloc((size_t)M * 4);
  float* maskf = (float*)alloc((size_t)M * 4);
  float* sres  = (float*)alloc((size_t)N * CO * 4);
  unsigned short* w1t = (unsigned short*)alloc((size_t)27 * CO * C * 2);
  unsigned short* w2t = (unsigned short*)alloc((size_t)27 * CO * CO * 2);
  float* pc = (float*)alloc((size_t)KP * M * CO * 4);   // k-split partials

  k_init<<<(G * G * G + 255) / 256, 256, 0, stream>>>(grid, h, h1);
  k_wt<C><<<(27 * C * CO + 255) / 256, 256, 0, stream>>>(c1w, w1t);
  k_wt<CO><<<(27 * CO * CO + 255) / 256, 256, 0, stream>>>(c2w, w2t);
  k_rownorm<<<N, 256, 0, stream>>>(feats, n1w, n1b, sdw, sdb,
                                   out + (size_t)M * CO, h, pidx, maskf);
  k_scatter<<<(M + 255) / 256, 256, 0, stream>>>(coords, grid);
  k_nidx<<<(M * 27 + 255) / 256, 256, 0, stream>>>(coords, grid, pidx, nidxt, g1t);
  k_skip<<<128, 256, 0, stream>>>(feats, skw, skb, sres);

  // conv1: CIN=256 (4 chunks of 64), k-split 7/7/7/6 -> 512 blocks
  k_conv<C, 4><<<dim3(M / 128, KP), 256, 0, stream>>>(h, g1t, w1t, pc);
  k_r1<<<M / 4, 256, 0, stream>>>(pc, c1b, h1);

  // conv2: CIN=128 (2 chunks of 64)
  k_conv<CO, 2><<<dim3(M / 128, KP), 256, 0, stream>>>(h1, nidxt, w2t, pc);
  k_r2<<<M * CO / 4 / 256, 256, 0, stream>>>(pc, c2b, sres, maskf, out);
}

// Round 4
// 206.371 us; speedup vs baseline: 3.1266x; 1.0167x over previous
//
#include <hip/hip_runtime.h>
#include <cstdint>
#include <cstddef>

// Problem constants (from reference)
constexpr int N  = 2048;     // parents
constexpr int C  = 256;      // in channels
constexpr int CO = 128;      // out channels
constexpr int M  = 16384;    // children (8*N)
constexpr int G  = 66;       // padded child grid dim (S2+2)
constexpr int KP = 7;        // k-split parts
constexpr int KCHUNK = 4;    // neighbors per part (4,4,4,4,4,4,3)
constexpr float EPS = 1e-6f;

using bf8 = __attribute__((ext_vector_type(8))) short;   // 8 bf16 (4 VGPRs)
using f4  = __attribute__((ext_vector_type(4))) float;   // 4 f32 acc

#define AS1 __attribute__((address_space(1)))
#define AS3 __attribute__((address_space(3)))

// async global->LDS DMA, 16B per lane; LDS dest = wave-uniform base + lane*16
static __device__ __forceinline__ void gl_lds16(const void* g, void* l) {
  __builtin_amdgcn_global_load_lds((AS1 const void*)g, (AS3 void*)l, 16, 0, 0);
}

static __device__ __forceinline__ unsigned short f2bf(float f) {
  unsigned u = __float_as_uint(f);
  u += 0x7fffu + ((u >> 16) & 1u);     // round-to-nearest-even
  return (unsigned short)(u >> 16);
}

// ---------------- init: grid sentinel + zero rows -----------------
__global__ void k_init(int* __restrict__ grid, unsigned short* __restrict__ h,
                       unsigned short* __restrict__ h1) {
  int i = blockIdx.x * 256 + threadIdx.x;
  if (i < G * G * G) grid[i] = M;
  if (i < C)  h[(size_t)N * C + i] = 0;
  if (i < CO) h1[(size_t)M * CO + i] = 0;
}

// ---------------- weight transpose [27][CIN][CO] f32 -> [27][CO][CIN] bf16 ----
template <int CIN>
__global__ void k_wt(const float* __restrict__ w, unsigned short* __restrict__ wt) {
  int i = blockIdx.x * 256 + threadIdx.x;
  if (i >= 27 * CIN * CO) return;
  int c = i % CIN;
  int rest = i / CIN;
  int o = rest % CO;
  int k = rest / CO;
  wt[i] = f2bf(w[((size_t)(k * CIN + c)) * CO + o]);
}

// ---------------- per-parent: subdiv + mask + LN + silu -> h (bf16) ----------
__global__ __launch_bounds__(256) void k_rownorm(
    const float* __restrict__ feats, const float* __restrict__ n1w,
    const float* __restrict__ n1b, const float* __restrict__ sdw,
    const float* __restrict__ sdb, float* __restrict__ out_subdiv,
    unsigned short* __restrict__ h, int* __restrict__ pidx,
    float* __restrict__ maskf) {
  int n = blockIdx.x, t = threadIdx.x;
  float x = feats[(size_t)n * C + t];
  float4 w0 = *(const float4*)(sdw + t * 8);
  float4 w1 = *(const float4*)(sdw + t * 8 + 4);
  float v[10] = {x * w0.x, x * w0.y, x * w0.z, x * w0.w,
                 x * w1.x, x * w1.y, x * w1.z, x * w1.w, x, x * x};
#pragma unroll
  for (int mk = 1; mk < 64; mk <<= 1) {
#pragma unroll
    for (int j = 0; j < 10; ++j) v[j] += __shfl_xor(v[j], mk, 64);
  }
  __shared__ float red[4][10];
  int wave = t >> 6, lane = t & 63;
  if (lane == 0) {
#pragma unroll
    for (int j = 0; j < 10; ++j) red[wave][j] = v[j];
  }
  __syncthreads();
  float sums[10];
#pragma unroll
  for (int j = 0; j < 10; ++j)
    sums[j] = red[0][j] + red[1][j] + red[2][j] + red[3][j];
  float mean = sums[8] / (float)C;
  float var  = sums[9] / (float)C - mean * mean;
  float rstd = rsqrtf(var + EPS);
  if (t < 8) {
    float sd = sums[t] + sdb[t];
    out_subdiv[(size_t)n * 8 + t] = sd;
    bool mk = sd > 0.f;
    pidx[n * 8 + t]  = mk ? n : N;   // h row index (N = zero row)
    maskf[n * 8 + t] = mk ? 1.f : 0.f;
  }
  float y  = (x - mean) * rstd * n1w[t] + n1b[t];
  float sl = y / (1.f + __expf(-y));
  h[(size_t)n * C + t] = f2bf(sl);
}

// ---------------- scatter child ids into grid --------------------------------
__global__ void k_scatter(const int* __restrict__ coords, int* __restrict__ grid) {
  int m = blockIdx.x * 256 + threadIdx.x;
  if (m >= M) return;
  int p = m >> 3, j = m & 7;
  int x = coords[p * 3 + 0] * 2 + ((j >> 2) & 1) + 1;
  int y = coords[p * 3 + 1] * 2 + ((j >> 1) & 1) + 1;
  int z = coords[p * 3 + 2] * 2 + (j & 1) + 1;
  grid[(x * G + y) * G + z] = m;
}

// ---------------- build transposed tables nidxt[k][M], g1t[k][M] -------------
__global__ void k_nidx(const int* __restrict__ coords, const int* __restrict__ grid,
                       const int* __restrict__ pidx, int* __restrict__ nidxt,
                       int* __restrict__ g1t) {
  int idx = blockIdx.x * 256 + threadIdx.x;
  if (idx >= M * 27) return;
  int m = idx & (M - 1);          // M = 2^14
  int k = idx >> 14;
  int p = m >> 3, j = m & 7;
  int dx = k / 9 - 1;
  int dy = (k / 3) % 3 - 1;
  int dz = k % 3 - 1;
  int x = coords[p * 3 + 0] * 2 + ((j >> 2) & 1) + 1 + dx;
  int y = coords[p * 3 + 1] * 2 + ((j >> 1) & 1) + 1 + dy;
  int z = coords[p * 3 + 2] * 2 + (j & 1) + 1 + dz;
  int gv = grid[(x * G + y) * G + z];
  nidxt[idx] = gv;                      // index into h1 (M = zero row)
  g1t[idx] = (gv == M) ? N : pidx[gv];  // index into h  (N = zero row)
}

// ---------------- skip GEMM: s = feats @ skip_w + skip_b  (f32) --------------
__global__ __launch_bounds__(256) void k_skip(const float* __restrict__ feats,
                                              const float* __restrict__ skw,
                                              const float* __restrict__ skb,
                                              float* __restrict__ s) {
  __shared__ float tile[32][36];
  int t = threadIdx.x;
  int rb = (blockIdx.x >> 1) * 32;        // 32 rows per block
  int ob = (blockIdx.x & 1) * 64;         // 64-col half
  int o = ob + (t & 63);
  int rg = (t >> 6) * 8;                  // 8 rows per wave-group
  float acc[8] = {0, 0, 0, 0, 0, 0, 0, 0};
  for (int cb = 0; cb < C; cb += 32) {
    __syncthreads();
    int row = t >> 3, cc = (t & 7) * 4;
    *(float4*)&tile[row][cc] =
        *(const float4*)(feats + (size_t)(rb + row) * C + cb + cc);
    __syncthreads();
    for (int c = 0; c < 32; ++c) {
      float wv = skw[(size_t)(cb + c) * CO + o];
#pragma unroll
      for (int r = 0; r < 8; ++r) acc[r] += tile[rg + r][c] * wv;
    }
  }
  float bv = skb[o];
#pragma unroll
  for (int r = 0; r < 8; ++r) s[(size_t)(rb + rg + r) * CO + o] = acc[r] + bv;
}

// ---------------- implicit-GEMM conv (MFMA + LDS double-buffer, K=32 stages) -
// Block: 128 rows x 128 cols, k-range KCHUNK (KP-way split). grid=(M/128, KP).
// Stage = one (k, 32-chan chunk): A 8KB gathered DMA, B 8KB DMA, dbuf = 32KB.
// Gather indices preloaded to registers. XOR slot swizzle (chunk^((row>>1)&3))
// -> frag ds_read_b128 2-way max (free). 4 waves (2x2), each 64x64.
template <int CIN, int NCB>
__global__ __launch_bounds__(256, 4) void k_conv(
    const unsigned short* __restrict__ src, const int* __restrict__ gt,
    const unsigned short* __restrict__ wt, float* __restrict__ part) {
  __shared__ unsigned short sA[2][128 * 32];   // 8 KB per buf
  __shared__ unsigned short sB[2][128 * 32];
  const int t = threadIdx.x;
  const int w = t >> 6, lane = t & 63;
  const int quad = lane >> 4, ln = lane & 15;
  const int m0 = blockIdx.x * 128;
  const int kpart = blockIdx.y;
  const int k0 = kpart * KCHUNK;
  const int nk = min(KCHUNK, 27 - k0);
  const int nstage = nk * NCB;
  const int rh = (w >> 1) * 64, ch = (w & 1) * 64;

  // staging lane constants: lane covers row (lane>>2) in its 16-row group,
  // stored slot lane&3, which holds global chunk gchunk = (lane&3)^((lane>>3)&3)
  // (so stored slot = chunk ^ ((row>>1)&3), row local = lane>>2).
  const int srow = lane >> 2;                  // row within 16-row group... x4 groups
  const int gchunk = (lane & 3) ^ ((lane >> 3) & 3);

  // preload gather indices: rows rr*64 + w*16 + (lane>>2) for each local k
  int ga[KCHUNK][2];
#pragma unroll
  for (int kk = 0; kk < KCHUNK; ++kk) {
#pragma unroll
    for (int rr = 0; rr < 2; ++rr) {
      ga[kk][rr] = (kk < nk)
          ? gt[(size_t)(k0 + kk) * M + m0 + rr * 64 + w * 16 + (lane >> 2)]
          : 0;
    }
  }
  (void)srow;

  auto stage = [&](int s, int buf) {
    const int kk = s / NCB;
    const int cb = s - kk * NCB;
    const int colbase = cb * 32 + gchunk * 8;  // element offset in source row
#pragma unroll
    for (int rr = 0; rr < 2; ++rr) {
      gl_lds16(src + (size_t)ga[kk][rr] * CIN + colbase,
               &sA[buf][(rr * 64 + w * 16) * 32]);
    }
#pragma unroll
    for (int rr = 0; rr < 2; ++rr) {
      const int corow = rr * 64 + w * 16 + (lane >> 2);
      gl_lds16(wt + ((size_t)(k0 + kk) * CO + corow) * CIN + colbase,
               &sB[buf][(rr * 64 + w * 16) * 32]);
    }
  };

  f4 acc[16];
  f4 zero = {0.f, 0.f, 0.f, 0.f};
#pragma unroll
  for (int i = 0; i < 16; ++i) acc[i] = zero;

  const int slot = quad ^ ((ln >> 1) & 3);     // de-swizzle for frag reads

  stage(0, 0);
  for (int s = 0; s < nstage; ++s) {
    __syncthreads();                 // staging of buf[s&1] done; prev readers done
    if (s + 1 < nstage) stage(s + 1, (s + 1) & 1);
    const unsigned short* pa = sA[s & 1];
    const unsigned short* pb = sB[s & 1];
    bf8 av[4], bv[4];
#pragma unroll
    for (int ti = 0; ti < 4; ++ti) {
      int row = rh + ti * 16 + ln;
      av[ti] = *(const bf8*)(pa + row * 32 + slot * 8);
    }
#pragma unroll
    for (int tj = 0; tj < 4; ++tj) {
      int row = ch + tj * 16 + ln;
      bv[tj] = *(const bf8*)(pb + row * 32 + slot * 8);
    }
#pragma unroll
    for (int ti = 0; ti < 4; ++ti)
#pragma unroll
      for (int tj = 0; tj < 4; ++tj)
        acc[ti * 4 + tj] = __builtin_amdgcn_mfma_f32_16x16x32_bf16(
            av[ti], bv[tj], acc[ti * 4 + tj], 0, 0, 0);
  }

  // store partials: D layout col=ln, row=quad*4+rr
  float* pp = part + ((size_t)kpart * M + m0) * CO;
#pragma unroll
  for (int ti = 0; ti < 4; ++ti) {
    int mrow = rh + ti * 16 + quad * 4;
#pragma unroll
    for (int tj = 0; tj < 4; ++tj) {
      int co = ch + tj * 16 + ln;
#pragma unroll
      for (int rr = 0; rr < 4; ++rr)
        pp[(size_t)(mrow + rr) * CO + co] = acc[ti * 4 + tj][rr];
    }
  }
}

// ---------------- reduce 1: sum KP partials + bias + LN + silu -> h1 bf16 ----
__global__ __launch_bounds__(256) void k_r1(const float* __restrict__ p,
                                            const float* __restrict__ bias,
                                            unsigned short* __restrict__ h1) {
  int wave = threadIdx.x >> 6, lane = threadIdx.x & 63;
  int m = blockIdx.x * 4 + wave;
  float v0 = bias[lane], v1 = bias[lane + 64];
#pragma unroll
  for (int q = 0; q < KP; ++q) {
    const float* pq = p + ((size_t)q * M + m) * CO;
    v0 += pq[lane];
    v1 += pq[lane + 64];
  }
  float sum = v0 + v1, sq = v0 * v0 + v1 * v1;
#pragma unroll
  for (int mk = 1; mk < 64; mk <<= 1) {
    sum += __shfl_xor(sum, mk, 64);
    sq  += __shfl_xor(sq, mk, 64);
  }
  float mean = sum / (float)CO;
  float var  = sq / (float)CO - mean * mean;
  float rstd = rsqrtf(var + EPS);
  float y0 = (v0 - mean) * rstd;
  float y1 = (v1 - mean) * rstd;
  float s0 = y0 / (1.f + __expf(-y0));
  float s1 = y1 / (1.f + __expf(-y1));
  h1[(size_t)m * CO + lane]      = f2bf(s0);
  h1[(size_t)m * CO + lane + 64] = f2bf(s1);
}

// ---------------- reduce 2: sum KP partials + bias + skip, *mask -> out ------
__global__ __launch_bounds__(256) void k_r2(const float* __restrict__ p,
                                            const float* __restrict__ bias,
                                            const float* __restrict__ sres,
                                            const float* __restrict__ maskf,
                                            float* __restrict__ out) {
  int i = blockIdx.x * 256 + threadIdx.x;   // i in [0, M*CO/4)
  int m = i >> 5;                            // 32 float4 per row
  int o4 = (i & 31) * 4;
  float4 acc = *(const float4*)(bias + o4);
#pragma unroll
  for (int q = 0; q < KP; ++q) {
    float4 a = *(const float4*)(p + ((size_t)q * M + m) * CO + o4);
    acc.x += a.x; acc.y += a.y; acc.z += a.z; acc.w += a.w;
  }
  float4 s = *(const float4*)(sres + (size_t)(m >> 3) * CO + o4);
  float mk = maskf[m];
  float4 r;
  r.x = (acc.x + s.x) * mk;
  r.y = (acc.y + s.y) * mk;
  r.z = (acc.z + s.z) * mk;
  r.w = (acc.w + s.w) * mk;
  *(float4*)(out + (size_t)m * CO + o4) = r;
}

// ---------------- launcher ----------------------------------------------------
extern "C" void kernel_launch(void* const* d_in, const int* in_sizes, int n_in,
                              void* d_out, int out_size, void* d_ws, size_t ws_size,
                              hipStream_t stream) {
  const float* feats = (const float*)d_in[0];
  const float* n1w   = (const float*)d_in[1];
  const float* n1b   = (const float*)d_in[2];
  const float* sdw   = (const float*)d_in[3];
  const float* sdb   = (const float*)d_in[4];
  const float* c1w   = (const float*)d_in[5];
  const float* c1b   = (const float*)d_in[6];
  const float* c2w   = (const float*)d_in[7];
  const float* c2b   = (const float*)d_in[8];
  const float* skw   = (const float*)d_in[9];
  const float* skb   = (const float*)d_in[10];
  const int* coords  = (const int*)d_in[11];
  float* out = (float*)d_out;   // [M*CO] conv output, then [N*8] subdiv

  char* ws = (char*)d_ws;
  size_t off = 0;
  auto alloc = [&](size_t bytes) -> char* {
    char* p = ws + off;
    off += (bytes + 255) & ~(size_t)255;
    return p;
  };
  unsigned short* h    = (unsigned short*)alloc((size_t)(N + 1) * C * 2);
  unsigned short* h1   = (unsigned short*)alloc((size_t)(M + 1) * CO * 2);
  int*   grid  = (int*)alloc((size_t)G * G * G * 4);
  int*   nidxt = (int*)alloc((size_t)27 * M * 4);
  int*   g1t   = (int*)alloc((size_t)27 * M * 4);
  int*   pidx  = (int*)alloc((size_t)M * 4);
  float* maskf = (float*)alloc((size_t)M * 4);
  float* sres  = (float*)alloc((size_t)N * CO * 4);
  unsigned short* w1t = (unsigned short*)alloc((size_t)27 * CO * C * 2);
  unsigned short* w2t = (unsigned short*)alloc((size_t)27 * CO * CO * 2);
  float* pc = (float*)alloc((size_t)KP * M * CO * 4);   // k-split partials

  k_init<<<(G * G * G + 255) / 256, 256, 0, stream>>>(grid, h, h1);
  k_wt<C><<<(27 * C * CO + 255) / 256, 256, 0, stream>>>(c1w, w1t);
  k_wt<CO><<<(27 * CO * CO + 255) / 256, 256, 0, stream>>>(c2w, w2t);
  k_rownorm<<<N, 256, 0, stream>>>(feats, n1w, n1b, sdw, sdb,
                                   out + (size_t)M * CO, h, pidx, maskf);
  k_scatter<<<(M + 255) / 256, 256, 0, stream>>>(coords, grid);
  k_nidx<<<(M * 27 + 255) / 256, 256, 0, stream>>>(coords, grid, pidx, nidxt, g1t);
  k_skip<<<128, 256, 0, stream>>>(feats, skw, skb, sres);

  // conv1: CIN=256 (8 chunks of 32), k-split 4x6+3 -> 896 blocks
  k_conv<C, 8><<<dim3(M / 128, KP), 256, 0, stream>>>(h, g1t, w1t, pc);
  k_r1<<<M / 4, 256, 0, stream>>>(pc, c1b, h1);

  // conv2: CIN=128 (4 chunks of 32)
  k_conv<CO, 4><<<dim3(M / 128, KP), 256, 0, stream>>>(h1, nidxt, w2t, pc);
  k_r2<<<M * CO / 4 / 256, 256, 0, stream>>>(pc, c2b, sres, maskf, out);
}

// Round 5
// 190.619 us; speedup vs baseline: 3.3849x; 1.0826x over previous
//
#include <hip/hip_runtime.h>
#include <cstdint>
#include <cstddef>

// Problem constants (from reference)
constexpr int N  = 2048;     // parents
constexpr int C  = 256;      // in channels
constexpr int CO = 128;      // out channels
constexpr int M  = 16384;    // children (8*N)
constexpr int G  = 66;       // padded child grid dim (S2+2)
constexpr int KP = 7;        // k-split parts
constexpr int KCHUNK = 4;    // neighbors per part (4,4,4,4,4,4,3)
constexpr float EPS = 1e-6f;

using bf8 = __attribute__((ext_vector_type(8))) short;   // 8 bf16 (4 VGPRs)
using f4  = __attribute__((ext_vector_type(4))) float;   // 4 f32 acc

static __device__ __forceinline__ unsigned short f2bf(float f) {
  unsigned u = __float_as_uint(f);
  u += 0x7fffu + ((u >> 16) & 1u);     // round-to-nearest-even
  return (unsigned short)(u >> 16);
}
static __device__ __forceinline__ float bf2f(unsigned short s) {
  return __uint_as_float((unsigned)s << 16);
}

// ---------------- prep: grid sentinel + zero rows + both weight transposes ---
__global__ void k_prep(int* __restrict__ grid, unsigned short* __restrict__ h,
                       unsigned short* __restrict__ h1,
                       const float* __restrict__ c1w, unsigned short* __restrict__ w1t,
                       const float* __restrict__ c2w, unsigned short* __restrict__ w2t) {
  int i = blockIdx.x * 256 + threadIdx.x;
  if (i < G * G * G) grid[i] = M;
  if (i < C)  h[(size_t)N * C + i] = 0;
  if (i < CO) h1[(size_t)M * CO + i] = 0;
  if (i < 27 * C * CO) {       // w1t[k][o][c] = c1w[k][c][o]
    int c = i % C;
    int rest = i / C;
    int o = rest % CO;
    int k = rest / CO;
    w1t[i] = f2bf(c1w[((size_t)(k * C + c)) * CO + o]);
  }
  if (i < 27 * CO * CO) {      // w2t[k][o][c] = c2w[k][c][o]
    int c = i % CO;
    int rest = i / CO;
    int o = rest % CO;
    int k = rest / CO;
    w2t[i] = f2bf(c2w[((size_t)(k * CO + c)) * CO + o]);
  }
}

// ------- per-parent: subdiv + mask + LN + silu -> h (bf16); + child scatter --
__global__ __launch_bounds__(256) void k_rownorm(
    const float* __restrict__ feats, const float* __restrict__ n1w,
    const float* __restrict__ n1b, const float* __restrict__ sdw,
    const float* __restrict__ sdb, float* __restrict__ out_subdiv,
    unsigned short* __restrict__ h, int* __restrict__ pidx,
    float* __restrict__ maskf, const int* __restrict__ coords,
    int* __restrict__ grid) {
  int n = blockIdx.x, t = threadIdx.x;
  float x = feats[(size_t)n * C + t];
  float4 w0 = *(const float4*)(sdw + t * 8);
  float4 w1 = *(const float4*)(sdw + t * 8 + 4);
  float v[10] = {x * w0.x, x * w0.y, x * w0.z, x * w0.w,
                 x * w1.x, x * w1.y, x * w1.z, x * w1.w, x, x * x};
#pragma unroll
  for (int mk = 1; mk < 64; mk <<= 1) {
#pragma unroll
    for (int j = 0; j < 10; ++j) v[j] += __shfl_xor(v[j], mk, 64);
  }
  __shared__ float red[4][10];
  int wave = t >> 6, lane = t & 63;
  if (lane == 0) {
#pragma unroll
    for (int j = 0; j < 10; ++j) red[wave][j] = v[j];
  }
  __syncthreads();
  float sums[10];
#pragma unroll
  for (int j = 0; j < 10; ++j)
    sums[j] = red[0][j] + red[1][j] + red[2][j] + red[3][j];
  float mean = sums[8] / (float)C;
  float var  = sums[9] / (float)C - mean * mean;
  float rstd = rsqrtf(var + EPS);
  if (t < 8) {
    float sd = sums[t] + sdb[t];
    out_subdiv[(size_t)n * 8 + t] = sd;
    bool mk = sd > 0.f;
    pidx[n * 8 + t]  = mk ? n : N;   // h row index (N = zero row)
    maskf[n * 8 + t] = mk ? 1.f : 0.f;
    // scatter child id into lookup grid (grid pre-inited to M by k_prep)
    int xx = coords[n * 3 + 0] * 2 + ((t >> 2) & 1) + 1;
    int yy = coords[n * 3 + 1] * 2 + ((t >> 1) & 1) + 1;
    int zz = coords[n * 3 + 2] * 2 + (t & 1) + 1;
    grid[(xx * G + yy) * G + zz] = n * 8 + t;
  }
  float y  = (x - mean) * rstd * n1w[t] + n1b[t];
  float sl = y / (1.f + __expf(-y));
  h[(size_t)n * C + t] = f2bf(sl);
}

// ---------------- build transposed tables nidxt[k][M], g1t[k][M] -------------
__global__ void k_nidx(const int* __restrict__ coords, const int* __restrict__ grid,
                       const int* __restrict__ pidx, int* __restrict__ nidxt,
                       int* __restrict__ g1t) {
  int idx = blockIdx.x * 256 + threadIdx.x;
  if (idx >= M * 27) return;
  int m = idx & (M - 1);          // M = 2^14
  int k = idx >> 14;
  int p = m >> 3, j = m & 7;
  int dx = k / 9 - 1;
  int dy = (k / 3) % 3 - 1;
  int dz = k % 3 - 1;
  int x = coords[p * 3 + 0] * 2 + ((j >> 2) & 1) + 1 + dx;
  int y = coords[p * 3 + 1] * 2 + ((j >> 1) & 1) + 1 + dy;
  int z = coords[p * 3 + 2] * 2 + (j & 1) + 1 + dz;
  int gv = grid[(x * G + y) * G + z];
  nidxt[idx] = gv;                      // index into h1 (M = zero row)
  g1t[idx] = (gv == M) ? N : pidx[gv];  // index into h  (N = zero row)
}

// ---------------- skip GEMM: s = feats @ skip_w + skip_b  (f32) --------------
__global__ __launch_bounds__(256) void k_skip(const float* __restrict__ feats,
                                              const float* __restrict__ skw,
                                              const float* __restrict__ skb,
                                              float* __restrict__ s) {
  __shared__ float tile[32][36];
  int t = threadIdx.x;
  int rb = (blockIdx.x >> 1) * 32;        // 32 rows per block
  int ob = (blockIdx.x & 1) * 64;         // 64-col half
  int o = ob + (t & 63);
  int rg = (t >> 6) * 8;                  // 8 rows per wave-group
  float acc[8] = {0, 0, 0, 0, 0, 0, 0, 0};
  for (int cb = 0; cb < C; cb += 32) {
    __syncthreads();
    int row = t >> 3, cc = (t & 7) * 4;
    *(float4*)&tile[row][cc] =
        *(const float4*)(feats + (size_t)(rb + row) * C + cb + cc);
    __syncthreads();
    for (int c = 0; c < 32; ++c) {
      float wv = skw[(size_t)(cb + c) * CO + o];
#pragma unroll
      for (int r = 0; r < 8; ++r) acc[r] += tile[rg + r][c] * wv;
    }
  }
  float bv = skb[o];
#pragma unroll
  for (int r = 0; r < 8; ++r) s[(size_t)(rb + rg + r) * CO + o] = acc[r] + bv;
}

// ---------------- implicit-GEMM conv: register-staged LDS pipeline -----------
// Block: 128 rows x 128 cols, k-range KCHUNK (KP-way split). grid=(M/128, KP).
// Stage (k, 32-chan chunk): each thread loads 2x16B of A (gathered) and 2x16B
// of B (weights) into VGPRs, MFMAs run on current LDS buffer, then regs are
// ds_written to the other buffer -> vmcnt wait overlaps the whole MFMA stage.
// One barrier per stage. XOR slot swizzle (chunk^((row>>1)&3)) keeps both
// ds_write_b128 and ds_read_b128 at the uniform 8-lane/bank width floor.
template <int CIN, int NCB>
__global__ __launch_bounds__(256, 3) void k_conv(
    const unsigned short* __restrict__ src, const int* __restrict__ gt,
    const unsigned short* __restrict__ wt, unsigned short* __restrict__ part) {
  __shared__ unsigned short sA[2][128 * 32];   // 8 KB per buf
  __shared__ unsigned short sB[2][128 * 32];
  const int t = threadIdx.x;
  const int w = t >> 6, lane = t & 63;
  const int quad = lane >> 4, ln = lane & 15;
  const int m0 = blockIdx.x * 128;
  const int kpart = blockIdx.y;
  const int k0 = kpart * KCHUNK;
  const int nk = min(KCHUNK, 27 - k0);
  const int nstage = nk * NCB;
  const int rh = (w >> 1) * 64, ch = (w & 1) * 64;

  // staging: thread covers tile row row2 = t>>1, global chunks c0, c0+1
  const int row2 = t >> 1;
  const int c0 = (t & 1) * 2;
  const int x3 = (row2 >> 1) & 3;
  const int wsl0 = row2 * 32 + ((c0) ^ x3) * 8;
  const int wsl1 = row2 * 32 + ((c0 + 1) ^ x3) * 8;

  // preload gather indices (one A row per thread per local k)
  int ga[KCHUNK];
#pragma unroll
  for (int kk = 0; kk < KCHUNK; ++kk)
    ga[kk] = (kk < nk) ? gt[(size_t)(k0 + kk) * M + m0 + row2] : 0;

  bf8 ra0, ra1, rb0, rb1;
  auto loadreg = [&](int s) {
    const int kk = s / NCB;
    const int cb = s - kk * NCB;
    const unsigned short* pa = src + (size_t)ga[kk] * CIN + cb * 32 + c0 * 8;
    const unsigned short* pb =
        wt + ((size_t)(k0 + kk) * CO + row2) * CIN + cb * 32 + c0 * 8;
    ra0 = *(const bf8*)(pa);
    ra1 = *(const bf8*)(pa + 8);
    rb0 = *(const bf8*)(pb);
    rb1 = *(const bf8*)(pb + 8);
  };
  auto writelds = [&](int buf) {
    *(bf8*)(sA[buf] + wsl0) = ra0;
    *(bf8*)(sA[buf] + wsl1) = ra1;
    *(bf8*)(sB[buf] + wsl0) = rb0;
    *(bf8*)(sB[buf] + wsl1) = rb1;
  };

  f4 acc[16];
  f4 zero = {0.f, 0.f, 0.f, 0.f};
#pragma unroll
  for (int i = 0; i < 16; ++i) acc[i] = zero;

  const int slot = (quad ^ ((ln >> 1) & 3)) * 8;   // de-swizzle for frag reads

  loadreg(0);
  writelds(0);
  for (int s = 0; s < nstage; ++s) {
    const bool have = (s + 1 < nstage);
    if (have) loadreg(s + 1);          // global->VGPR, overlaps this stage
    __syncthreads();                   // stage-s LDS writes visible
    const unsigned short* pa = sA[s & 1];
    const unsigned short* pb = sB[s & 1];
    bf8 av[4], bv[4];
#pragma unroll
    for (int ti = 0; ti < 4; ++ti)
      av[ti] = *(const bf8*)(pa + (rh + ti * 16 + ln) * 32 + slot);
#pragma unroll
    for (int tj = 0; tj < 4; ++tj)
      bv[tj] = *(const bf8*)(pb + (ch + tj * 16 + ln) * 32 + slot);
#pragma unroll
    for (int ti = 0; ti < 4; ++ti)
#pragma unroll
      for (int tj = 0; tj < 4; ++tj)
        acc[ti * 4 + tj] = __builtin_amdgcn_mfma_f32_16x16x32_bf16(
            av[ti], bv[tj], acc[ti * 4 + tj], 0, 0, 0);
    if (have) writelds((s + 1) & 1);   // vmcnt wait lands here, post-MFMA
  }

  // store bf16 partials: D layout col=ln, row=quad*4+rr
  unsigned short* pp = part + ((size_t)kpart * M + m0) * CO;
#pragma unroll
  for (int ti = 0; ti < 4; ++ti) {
    int mrow = rh + ti * 16 + quad * 4;
#pragma unroll
    for (int tj = 0; tj < 4; ++tj) {
      int co = ch + tj * 16 + ln;
#pragma unroll
      for (int rr = 0; rr < 4; ++rr)
        pp[(size_t)(mrow + rr) * CO + co] = f2bf(acc[ti * 4 + tj][rr]);
    }
  }
}

// ---------------- reduce 1: sum KP bf16 partials + bias + LN + silu -> h1 ----
__global__ __launch_bounds__(256) void k_r1(const unsigned short* __restrict__ p,
                                            const float* __restrict__ bias,
                                            unsigned short* __restrict__ h1) {
  int wave = threadIdx.x >> 6, lane = threadIdx.x & 63;
  int m = blockIdx.x * 4 + wave;
  float v0 = bias[lane], v1 = bias[lane + 64];
#pragma unroll
  for (int q = 0; q < KP; ++q) {
    const unsigned short* pq = p + ((size_t)q * M + m) * CO;
    v0 += bf2f(pq[lane]);
    v1 += bf2f(pq[lane + 64]);
  }
  float sum = v0 + v1, sq = v0 * v0 + v1 * v1;
#pragma unroll
  for (int mk = 1; mk < 64; mk <<= 1) {
    sum += __shfl_xor(sum, mk, 64);
    sq  += __shfl_xor(sq, mk, 64);
  }
  float mean = sum / (float)CO;
  float var  = sq / (float)CO - mean * mean;
  float rstd = rsqrtf(var + EPS);
  float y0 = (v0 - mean) * rstd;
  float y1 = (v1 - mean) * rstd;
  float s0 = y0 / (1.f + __expf(-y0));
  float s1 = y1 / (1.f + __expf(-y1));
  h1[(size_t)m * CO + lane]      = f2bf(s0);
  h1[(size_t)m * CO + lane + 64] = f2bf(s1);
}

// ---------------- reduce 2: sum KP bf16 partials + bias + skip, *mask -> out -
__global__ __launch_bounds__(256) void k_r2(const unsigned short* __restrict__ p,
                                            const float* __restrict__ bias,
                                            const float* __restrict__ sres,
                                            const float* __restrict__ maskf,
                                            float* __restrict__ out) {
  int i = blockIdx.x * 256 + threadIdx.x;   // i in [0, M*CO/4)
  int m = i >> 5;                            // 32 groups of 4 per row
  int o4 = (i & 31) * 4;
  float4 acc = *(const float4*)(bias + o4);
#pragma unroll
  for (int q = 0; q < KP; ++q) {
    ushort4 a = *(const ushort4*)(p + ((size_t)q * M + m) * CO + o4);
    acc.x += bf2f(a.x); acc.y += bf2f(a.y);
    acc.z += bf2f(a.z); acc.w += bf2f(a.w);
  }
  float4 s = *(const float4*)(sres + (size_t)(m >> 3) * CO + o4);
  float mk = maskf[m];
  float4 r;
  r.x = (acc.x + s.x) * mk;
  r.y = (acc.y + s.y) * mk;
  r.z = (acc.z + s.z) * mk;
  r.w = (acc.w + s.w) * mk;
  *(float4*)(out + (size_t)m * CO + o4) = r;
}

// ---------------- launcher ----------------------------------------------------
extern "C" void kernel_launch(void* const* d_in, const int* in_sizes, int n_in,
                              void* d_out, int out_size, void* d_ws, size_t ws_size,
                              hipStream_t stream) {
  const float* feats = (const float*)d_in[0];
  const float* n1w   = (const float*)d_in[1];
  const float* n1b   = (const float*)d_in[2];
  const float* sdw   = (const float*)d_in[3];
  const float* sdb   = (const float*)d_in[4];
  const float* c1w   = (const float*)d_in[5];
  const float* c1b   = (const float*)d_in[6];
  const float* c2w   = (const float*)d_in[7];
  const float* c2b   = (const float*)d_in[8];
  const float* skw   = (const float*)d_in[9];
  const float* skb   = (const float*)d_in[10];
  const int* coords  = (const int*)d_in[11];
  float* out = (float*)d_out;   // [M*CO] conv output, then [N*8] subdiv

  char* ws = (char*)d_ws;
  size_t off = 0;
  auto alloc = [&](size_t bytes) -> char* {
    char* p = ws + off;
    off += (bytes + 255) & ~(size_t)255;
    return p;
  };
  unsigned short* h    = (unsigned short*)alloc((size_t)(N + 1) * C * 2);
  unsigned short* h1   = (unsigned short*)alloc((size_t)(M + 1) * CO * 2);
  int*   grid  = (int*)alloc((size_t)G * G * G * 4);
  int*   nidxt = (int*)alloc((size_t)27 * M * 4);
  int*   g1t   = (int*)alloc((size_t)27 * M * 4);
  int*   pidx  = (int*)alloc((size_t)M * 4);
  float* maskf = (float*)alloc((size_t)M * 4);
  float* sres  = (float*)alloc((size_t)N * CO * 4);
  unsigned short* w1t = (unsigned short*)alloc((size_t)27 * CO * C * 2);
  unsigned short* w2t = (unsigned short*)alloc((size_t)27 * CO * CO * 2);
  unsigned short* pc  = (unsigned short*)alloc((size_t)KP * M * CO * 2);

  k_prep<<<(27 * C * CO + 255) / 256, 256, 0, stream>>>(grid, h, h1, c1w, w1t,
                                                        c2w, w2t);
  k_rownorm<<<N, 256, 0, stream>>>(feats, n1w, n1b, sdw, sdb,
                                   out + (size_t)M * CO, h, pidx, maskf,
                                   coords, grid);
  k_nidx<<<(M * 27 + 255) / 256, 256, 0, stream>>>(coords, grid, pidx, nidxt, g1t);
  k_skip<<<128, 256, 0, stream>>>(feats, skw, skb, sres);

  // conv1: CIN=256 (8 chunks of 32), k-split 6x4+3 -> 896 blocks
  k_conv<C, 8><<<dim3(M / 128, KP), 256, 0, stream>>>(h, g1t, w1t, pc);
  k_r1<<<M / 4, 256, 0, stream>>>(pc, c1b, h1);

  // conv2: CIN=128 (4 chunks of 32)
  k_conv<CO, 4><<<dim3(M / 128, KP), 256, 0, stream>>>(h1, nidxt, w2t, pc);
  k_r2<<<M * CO / 4 / 256, 256, 0, stream>>>(pc, c2b, sres, maskf, out);
}